// Round 6
// baseline (53.072 us; speedup 1.0000x reference)
//
#include <hip/hip_runtime.h>

#define EPSF 1e-8f
#define MARGINF 0.5f
#define BN 512
#define DD 768
#define BT 64
#define SPLITK 8
#define KC (DD / SPLITK)  // 96

typedef __attribute__((ext_vector_type(8))) short bf16x8;
typedef __attribute__((ext_vector_type(4))) float f32x4;

__device__ __forceinline__ short f2bf(float f) {
    unsigned int u = __float_as_uint(f);
    return (short)((u + 0x7FFFu + ((u >> 16) & 1u)) >> 16);  // RNE
}

__device__ __forceinline__ bf16x8 pack8(const float4& a, const float4& b) {
    bf16x8 r;
    r[0] = f2bf(a.x); r[1] = f2bf(a.y); r[2] = f2bf(a.z); r[3] = f2bf(a.w);
    r[4] = f2bf(b.x); r[5] = f2bf(b.y); r[6] = f2bf(b.z); r[7] = f2bf(b.w);
    return r;
}

// ---------------- Node 1: MFMA gram partials (blocks 0..511) + norms (512..519) ----------------
// Block b<512 -> (bz,bi,bj): dotp[bz][i][j] = sum_{k in 96-chunk bz} x_i . x_j  (bf16 inputs, f32 acc)
// Wave w owns rows w*16 of the 64x64 tile, 4 col-fragments, 3 k-steps. No LDS, no barriers.
__global__ __launch_bounds__(256) void prep_kernel(const float* __restrict__ x,
                                                   float* __restrict__ invn,
                                                   float* __restrict__ dotp,
                                                   double* __restrict__ acc,
                                                   unsigned int* __restrict__ ctr) {
    int b = blockIdx.x;
    int t = threadIdx.x;

    if (b >= BN) {
        // ----- norm task: 8 blocks x 64 rows, one wave per row -----
        if (b == BN && t == 0) { acc[0] = 0.0; acc[1] = 0.0; ctr[0] = 0u; }
        int rbase = (b - BN) * 64;
        int w = t >> 6, lane = t & 63;
        for (int r = w; r < 64; r += 4) {
            int row = rbase + r;
            float s = 0.f;
#pragma unroll
            for (int c = 0; c < 3; ++c) {
                float4 v = *(const float4*)&x[row * DD + (lane + c * 64) * 4];
                s += v.x * v.x + v.y * v.y + v.z * v.z + v.w * v.w;
            }
            for (int off = 32; off; off >>= 1) s += __shfl_down(s, off, 64);
            if (lane == 0) invn[row] = 1.0f / fmaxf(sqrtf(s), EPSF);
        }
        return;
    }

    int bz = b >> 6, bi = (b >> 3) & 7, bj = b & 7;
    int i0 = bi * BT, j0 = bj * BT, kbase = bz * KC;
    int wv = t >> 6, lane = t & 63;
    int r16 = lane & 15;          // A row / B col / C col within fragment
    int kb8 = (lane >> 4) * 8;    // k sub-offset within a 32-wide k-step

    const float* ax = &x[(i0 + wv * 16 + r16) * DD + kbase + kb8];
    const float* bx = &x[(j0 + r16) * DD + kbase + kb8];

    f32x4 accf[4];
#pragma unroll
    for (int c = 0; c < 4; ++c) accf[c] = (f32x4){0.f, 0.f, 0.f, 0.f};

#pragma unroll
    for (int s = 0; s < 3; ++s) {
        float4 a0 = *(const float4*)(ax + s * 32);
        float4 a1 = *(const float4*)(ax + s * 32 + 4);
        bf16x8 af = pack8(a0, a1);
#pragma unroll
        for (int c = 0; c < 4; ++c) {
            const float* bp = bx + c * 16 * DD + s * 32;
            float4 b0 = *(const float4*)(bp);
            float4 b1 = *(const float4*)(bp + 4);
            bf16x8 bf_ = pack8(b0, b1);
            accf[c] = __builtin_amdgcn_mfma_f32_16x16x32_bf16(af, bf_, accf[c], 0, 0, 0);
        }
    }

    // C/D layout: col = lane&15, row = (lane>>4)*4 + reg   [verified m89/m91]
    float* o = dotp + (size_t)bz * BN * BN;
    int crow = i0 + wv * 16 + (lane >> 4) * 4;
#pragma unroll
    for (int c = 0; c < 4; ++c) {
        int ccol = j0 + c * 16 + r16;
#pragma unroll
        for (int r = 0; r < 4; ++r)
            o[(crow + r) * BN + ccol] = accf[c][r];
    }
}

// ---------------- Node 2: triplet accumulation + fused finalize ----------------
__global__ __launch_bounds__(256) void triplet_kernel(const float* __restrict__ dotp,
                                                      const float* __restrict__ invn,
                                                      const int* __restrict__ labels,
                                                      double* __restrict__ acc,
                                                      unsigned int* __restrict__ ctr,
                                                      float* __restrict__ out) {
    int i = blockIdx.x;
    int t = threadIdx.x;
    __shared__ float drow[BN];
    __shared__ int lab[BN];
    __shared__ unsigned long long pmask[8];
    __shared__ float redf[4];
    __shared__ unsigned int redc[4];
    lab[t] = labels[t];
    lab[t + 256] = labels[t + 256];
    float inv_i = invn[i];
#pragma unroll
    for (int e0 = 0; e0 < BN; e0 += 256) {
        int e = e0 + t;
        float s = 0.f;
#pragma unroll
        for (int z = 0; z < SPLITK; ++z) s += dotp[(size_t)z * BN * BN + i * BN + e];
        drow[e] = 1.0f - s * inv_i * invn[e];
    }
    __syncthreads();
    int li = lab[i];
    if (t < 64) {
        for (int w = 0; w < 8; ++w) {
            int j = (w << 6) | t;
            unsigned long long m = __ballot(lab[j] == li && j != i);
            if (t == 0) pmask[w] = m;
        }
    }
    __syncthreads();
    float dik0 = drow[t];
    float dik1 = drow[t + 256];
    bool k0ok = (lab[t] != li);
    bool k1ok = (lab[t + 256] != li);
    float sum = 0.f;
    unsigned int cnt = 0;
    for (int w = 0; w < 8; ++w) {
        unsigned long long m = pmask[w];
        while (m) {
            int j = (w << 6) + __ffsll(m) - 1;
            m &= m - 1;
            float base = drow[j] + MARGINF;
            float v0 = base - dik0;
            float v1 = base - dik1;
            if (k0ok) {
                if (v0 > 0.f) sum += v0;
                if (v0 > EPSF) cnt++;
            }
            if (k1ok) {
                if (v1 > 0.f) sum += v1;
                if (v1 > EPSF) cnt++;
            }
        }
    }
    for (int off = 32; off; off >>= 1) {
        sum += __shfl_down(sum, off, 64);
        cnt += __shfl_down(cnt, off, 64);
    }
    if ((t & 63) == 0) { redf[t >> 6] = sum; redc[t >> 6] = cnt; }
    __syncthreads();
    if (t == 0) {
        float stot = redf[0] + redf[1] + redf[2] + redf[3];
        unsigned int ctot = redc[0] + redc[1] + redc[2] + redc[3];
        atomicAdd(&acc[0], (double)stot);
        atomicAdd(&acc[1], (double)ctot);
        __threadfence();
        unsigned int old = atomicAdd(ctr, 1u);
        if (old == BN - 1) {
            __threadfence();
            double s = atomicAdd(&acc[0], 0.0);   // RMW read at coherence point
            double c = atomicAdd(&acc[1], 0.0);
            out[0] = (float)(s / (c + 1e-8));
        }
    }
}

extern "C" void kernel_launch(void* const* d_in, const int* in_sizes, int n_in,
                              void* d_out, int out_size, void* d_ws, size_t ws_size,
                              hipStream_t stream) {
    const float* x = (const float*)d_in[0];
    const int* labels = (const int*)d_in[1];
    float* out = (float*)d_out;

    char* ws = (char*)d_ws;
    double* acc = (double*)ws;                    // 16 B
    unsigned int* ctr = (unsigned int*)(ws + 16); // 4 B
    float* invn = (float*)(ws + 256);             // 2 KB
    float* dotp = (float*)(ws + 4096);            // 8 MB

    prep_kernel<<<BN + 8, 256, 0, stream>>>(x, invn, dotp, acc, ctr);
    triplet_kernel<<<BN, 256, 0, stream>>>(dotp, invn, labels, acc, ctr, out);
}

// Round 7
// 48.068 us; speedup vs baseline: 1.1041x; 1.1041x over previous
//
#include <hip/hip_runtime.h>

#define EPSF 1e-8f
#define MARGINF 0.5f
#define BN 512
#define DD 768
#define BT 64
#define SPLITK 8
#define KC (DD / SPLITK)  // 96
#define LPAD 104          // shorts per LDS row: 52 dwords, 52%32=20 -> <=2-way on frag reads

typedef __attribute__((ext_vector_type(8))) short bf16x8;
typedef __attribute__((ext_vector_type(4))) float f32x4;

__device__ __forceinline__ short f2bf(float f) {
    unsigned int u = __float_as_uint(f);
    return (short)((u + 0x7FFFu + ((u >> 16) & 1u)) >> 16);  // RNE
}

__device__ __forceinline__ bf16x8 pack8(const float4& a, const float4& b) {
    bf16x8 r;
    r[0] = f2bf(a.x); r[1] = f2bf(a.y); r[2] = f2bf(a.z); r[3] = f2bf(a.w);
    r[4] = f2bf(b.x); r[5] = f2bf(b.y); r[6] = f2bf(b.z); r[7] = f2bf(b.w);
    return r;
}

// ---------------- Node 1: MFMA gram partials (blocks 0..511) + norms (512..519) ----------------
// Block b<512 -> (bz,bi,bj): dotp[bz][i][j] = sum_{k in 96-chunk bz} x_i . x_j
// Tiles staged once to LDS as bf16 (pack once, no per-wave duplication), one barrier,
// then 15 ds_read_b128 + 12 MFMA per wave. C/D layout verified in R6 (absmax 0.0).
__global__ __launch_bounds__(256) void prep_kernel(const float* __restrict__ x,
                                                   float* __restrict__ invn,
                                                   float* __restrict__ dotp,
                                                   double* __restrict__ acc,
                                                   unsigned int* __restrict__ ctr) {
    int b = blockIdx.x;
    int t = threadIdx.x;

    if (b >= BN) {
        // ----- norm task: 8 blocks x 64 rows, one wave per row -----
        if (b == BN && t == 0) { acc[0] = 0.0; acc[1] = 0.0; ctr[0] = 0u; }
        int rbase = (b - BN) * 64;
        int w = t >> 6, lane = t & 63;
        for (int r = w; r < 64; r += 4) {
            int row = rbase + r;
            float s = 0.f;
#pragma unroll
            for (int c = 0; c < 3; ++c) {
                float4 v = *(const float4*)&x[row * DD + (lane + c * 64) * 4];
                s += v.x * v.x + v.y * v.y + v.z * v.z + v.w * v.w;
            }
            for (int off = 32; off; off >>= 1) s += __shfl_down(s, off, 64);
            if (lane == 0) invn[row] = 1.0f / fmaxf(sqrtf(s), EPSF);
        }
        return;
    }

    __shared__ __align__(16) short As[BT][LPAD];   // 13.3 KB
    __shared__ __align__(16) short Bs[BT][LPAD];   // 26.6 KB total
    int bz = b >> 6, bi = (b >> 3) & 7, bj = b & 7;
    int i0 = bi * BT, j0 = bj * BT, kbase = bz * KC;

    // ----- cooperative stage: thread t -> row t>>2, float-octet (t&3) of each 32-float step -----
    {
        int row = t >> 2, fq = t & 3;
        const float* ap = &x[(i0 + row) * DD + kbase + fq * 8];
        const float* bp = &x[(j0 + row) * DD + kbase + fq * 8];
#pragma unroll
        for (int cc = 0; cc < 3; ++cc) {
            float4 a0 = *(const float4*)(ap + cc * 32);
            float4 a1 = *(const float4*)(ap + cc * 32 + 4);
            float4 b0 = *(const float4*)(bp + cc * 32);
            float4 b1 = *(const float4*)(bp + cc * 32 + 4);
            *(bf16x8*)&As[row][fq * 8 + cc * 32] = pack8(a0, a1);
            *(bf16x8*)&Bs[row][fq * 8 + cc * 32] = pack8(b0, b1);
        }
    }
    __syncthreads();

    // ----- MFMA: wave wv owns rows wv*16, 4 col-fragments, 3 k-steps -----
    int wv = t >> 6, lane = t & 63;
    int r16 = lane & 15;         // A row / B col within fragment
    int kb8 = (lane >> 4) * 8;   // k sub-offset within 32-wide k-step

    f32x4 accf[4];
#pragma unroll
    for (int c = 0; c < 4; ++c) accf[c] = (f32x4){0.f, 0.f, 0.f, 0.f};

#pragma unroll
    for (int s = 0; s < 3; ++s) {
        bf16x8 af = *(const bf16x8*)&As[wv * 16 + r16][kb8 + s * 32];
#pragma unroll
        for (int c = 0; c < 4; ++c) {
            bf16x8 bf_ = *(const bf16x8*)&Bs[c * 16 + r16][kb8 + s * 32];
            accf[c] = __builtin_amdgcn_mfma_f32_16x16x32_bf16(af, bf_, accf[c], 0, 0, 0);
        }
    }

    // C/D layout: col = lane&15, row = (lane>>4)*4 + reg   [verified m89/m91 + R6 run]
    float* o = dotp + (size_t)bz * BN * BN;
    int crow = i0 + wv * 16 + (lane >> 4) * 4;
#pragma unroll
    for (int c = 0; c < 4; ++c) {
        int ccol = j0 + c * 16 + r16;
#pragma unroll
        for (int r = 0; r < 4; ++r)
            o[(crow + r) * BN + ccol] = accf[c][r];
    }
}

// ---------------- Node 2: triplet accumulation + fused finalize ----------------
__global__ __launch_bounds__(256) void triplet_kernel(const float* __restrict__ dotp,
                                                      const float* __restrict__ invn,
                                                      const int* __restrict__ labels,
                                                      double* __restrict__ acc,
                                                      unsigned int* __restrict__ ctr,
                                                      float* __restrict__ out) {
    int i = blockIdx.x;
    int t = threadIdx.x;
    __shared__ float drow[BN];
    __shared__ int lab[BN];
    __shared__ unsigned long long pmask[8];
    __shared__ float redf[4];
    __shared__ unsigned int redc[4];
    lab[t] = labels[t];
    lab[t + 256] = labels[t + 256];
    float inv_i = invn[i];
#pragma unroll
    for (int e0 = 0; e0 < BN; e0 += 256) {
        int e = e0 + t;
        float s = 0.f;
#pragma unroll
        for (int z = 0; z < SPLITK; ++z) s += dotp[(size_t)z * BN * BN + i * BN + e];
        drow[e] = 1.0f - s * inv_i * invn[e];
    }
    __syncthreads();
    int li = lab[i];
    if (t < 64) {
        for (int w = 0; w < 8; ++w) {
            int j = (w << 6) | t;
            unsigned long long m = __ballot(lab[j] == li && j != i);
            if (t == 0) pmask[w] = m;
        }
    }
    __syncthreads();
    float dik0 = drow[t];
    float dik1 = drow[t + 256];
    bool k0ok = (lab[t] != li);
    bool k1ok = (lab[t + 256] != li);
    float sum = 0.f;
    unsigned int cnt = 0;
    for (int w = 0; w < 8; ++w) {
        unsigned long long m = pmask[w];
        while (m) {
            int j = (w << 6) + __ffsll(m) - 1;
            m &= m - 1;
            float base = drow[j] + MARGINF;
            float v0 = base - dik0;
            float v1 = base - dik1;
            if (k0ok) {
                if (v0 > 0.f) sum += v0;
                if (v0 > EPSF) cnt++;
            }
            if (k1ok) {
                if (v1 > 0.f) sum += v1;
                if (v1 > EPSF) cnt++;
            }
        }
    }
    for (int off = 32; off; off >>= 1) {
        sum += __shfl_down(sum, off, 64);
        cnt += __shfl_down(cnt, off, 64);
    }
    if ((t & 63) == 0) { redf[t >> 6] = sum; redc[t >> 6] = cnt; }
    __syncthreads();
    if (t == 0) {
        float stot = redf[0] + redf[1] + redf[2] + redf[3];
        unsigned int ctot = redc[0] + redc[1] + redc[2] + redc[3];
        atomicAdd(&acc[0], (double)stot);
        atomicAdd(&acc[1], (double)ctot);
        __threadfence();
        unsigned int old = atomicAdd(ctr, 1u);
        if (old == BN - 1) {
            __threadfence();
            double s = atomicAdd(&acc[0], 0.0);   // RMW read at coherence point
            double c = atomicAdd(&acc[1], 0.0);
            out[0] = (float)(s / (c + 1e-8));
        }
    }
}

extern "C" void kernel_launch(void* const* d_in, const int* in_sizes, int n_in,
                              void* d_out, int out_size, void* d_ws, size_t ws_size,
                              hipStream_t stream) {
    const float* x = (const float*)d_in[0];
    const int* labels = (const int*)d_in[1];
    float* out = (float*)d_out;

    char* ws = (char*)d_ws;
    double* acc = (double*)ws;                    // 16 B
    unsigned int* ctr = (unsigned int*)(ws + 16); // 4 B
    float* invn = (float*)(ws + 256);             // 2 KB
    float* dotp = (float*)(ws + 4096);            // 8 MB

    prep_kernel<<<BN + 8, 256, 0, stream>>>(x, invn, dotp, acc, ctr);
    triplet_kernel<<<BN, 256, 0, stream>>>(dotp, invn, labels, acc, ctr, out);
}